// Round 3
// baseline (50.777 us; speedup 1.0000x reference)
//
#include <hip/hip_runtime.h>
#include <math.h>

// out[m] = s*(1-s) * (W[m,:] @ (x_f - x_i)),  s = sigmoid(W[m,:] @ x_i + b[m])
// D = M = 8192, W fp32 row-major. HBM-bound on the single pass over W (268 MB).
//
// R3: back to R1 geometry (1024 thr / 16 waves / 1 row per wave, 32 waves/CU).
//  + W-row register prefetch issued BEFORE the x-staging barrier (W loads are
//    LDS-independent -> they stream from cycle 0, hiding the staging latency).
//  + 4-deep software pipeline in the main loop (load group k+1 while FMA group k).
//  + __launch_bounds__(1024, 8) to force VGPR<=64 so 2 blocks/CU co-reside.

constexpr int D_DIM = 8192;
constexpr int BLOCK = 1024;           // 16 waves
constexpr int ROWS_PER_BLOCK = 16;    // one row per wave
constexpr int NCHUNK = D_DIM / 4;     // 2048 float4 per row
constexpr int KPW = NCHUNK / 64;      // 32 chunks per lane per row

__global__ __launch_bounds__(BLOCK, 8)
void dyn_fused_kernel(const float* __restrict__ x_i,
                      const float* __restrict__ x_f,
                      const float* __restrict__ W,
                      const float* __restrict__ b,
                      float* __restrict__ out,
                      int M)
{
    __shared__ float4 s_xi[NCHUNK];   // 32 KiB
    __shared__ float4 s_v[NCHUNK];    // 32 KiB

    const int tid  = threadIdx.x;
    const int wave = tid >> 6;
    const int lane = tid & 63;
    const int row  = blockIdx.x * ROWS_PER_BLOCK + wave;

    const float4* Wr = reinterpret_cast<const float4*>(W + (size_t)row * D_DIM);

    // ---- Prefetch first 4 W chunks of this wave's row (independent of LDS) ----
    float4 p0 = Wr[lane +   0];
    float4 p1 = Wr[lane +  64];
    float4 p2 = Wr[lane + 128];
    float4 p3 = Wr[lane + 192];

    // ---- Stage x_i and v = x_f - x_i into LDS (overlaps with W prefetch) ----
    const float4* xi_g = reinterpret_cast<const float4*>(x_i);
    const float4* xf_g = reinterpret_cast<const float4*>(x_f);
    #pragma unroll
    for (int c = tid; c < NCHUNK; c += BLOCK) {
        float4 a = xi_g[c];
        float4 f = xf_g[c];
        s_xi[c] = a;
        s_v[c]  = make_float4(f.x - a.x, f.y - a.y, f.z - a.z, f.w - a.w);
    }
    __syncthreads();

    float acc_i = 0.0f;   // W[m]·x_i
    float acc_v = 0.0f;   // W[m]·v

#define FMA8(wv, c)                                                  \
    {                                                                \
        float4 xi = s_xi[(c)];                                       \
        float4 vv = s_v[(c)];                                        \
        acc_i = fmaf(wv.x, xi.x, acc_i);                             \
        acc_i = fmaf(wv.y, xi.y, acc_i);                             \
        acc_i = fmaf(wv.z, xi.z, acc_i);                             \
        acc_i = fmaf(wv.w, xi.w, acc_i);                             \
        acc_v = fmaf(wv.x, vv.x, acc_v);                             \
        acc_v = fmaf(wv.y, vv.y, acc_v);                             \
        acc_v = fmaf(wv.z, vv.z, acc_v);                             \
        acc_v = fmaf(wv.w, vv.w, acc_v);                             \
    }

    // ---- Main loop: FMA on group k while group k+1 loads (4-deep pipeline) ----
    #pragma unroll 1
    for (int k = 0; k < KPW - 4; k += 4) {
        const int base = lane + (k + 4) * 64;
        float4 n0 = Wr[base +   0];
        float4 n1 = Wr[base +  64];
        float4 n2 = Wr[base + 128];
        float4 n3 = Wr[base + 192];
        const int cb = lane + k * 64;
        FMA8(p0, cb +   0);
        FMA8(p1, cb +  64);
        FMA8(p2, cb + 128);
        FMA8(p3, cb + 192);
        p0 = n0; p1 = n1; p2 = n2; p3 = n3;
    }
    {   // epilogue: last 4 chunks
        const int cb = lane + (KPW - 4) * 64;
        FMA8(p0, cb +   0);
        FMA8(p1, cb +  64);
        FMA8(p2, cb + 128);
        FMA8(p3, cb + 192);
    }
#undef FMA8

    // ---- 64-lane butterfly reduction ----
    #pragma unroll
    for (int off = 32; off > 0; off >>= 1) {
        acc_i += __shfl_down(acc_i, off, 64);
        acc_v += __shfl_down(acc_v, off, 64);
    }

    if (lane == 0) {
        float z = acc_i + b[row];
        float s = 1.0f / (1.0f + expf(-z));
        out[row] = s * (1.0f - s) * acc_v;
    }
}

extern "C" void kernel_launch(void* const* d_in, const int* in_sizes, int n_in,
                              void* d_out, int out_size, void* d_ws, size_t ws_size,
                              hipStream_t stream) {
    // setup_inputs order: t(1), y(M), x_i(D), x_f(D), W(M*D), b(M)
    const float* x_i = (const float*)d_in[2];
    const float* x_f = (const float*)d_in[3];
    const float* W   = (const float*)d_in[4];
    const float* b   = (const float*)d_in[5];
    float* out = (float*)d_out;
    const int M = out_size;   // 8192

    const int grid = M / ROWS_PER_BLOCK;  // 512
    dyn_fused_kernel<<<grid, BLOCK, 0, stream>>>(x_i, x_f, W, b, out, M);
}

// Round 4
// 44.035 us; speedup vs baseline: 1.1531x; 1.1531x over previous
//
#include <hip/hip_runtime.h>
#include <math.h>

// out[m] = s*(1-s) * (W[m,:] @ (x_f - x_i)),  s = sigmoid(W[m,:] @ x_i + b[m])
// D = M = 8192, W fp32 row-major. Pure HBM-read-bound (W = 256 MiB, exactly L3
// size, streamed cyclically -> no L3 reuse; ceiling ~6.3 TB/s -> ~42 us).
//
// R4: drop LDS staging entirely (guide common-mistake #7: x fits L1/L2).
//  - x_i / x_f read directly from global each chunk: 64 KB working set,
//    L1/L2-hit; all waves walk it in the same order.
//  - W.v computed as (W.x_f - W.x_i) after reduction -> no per-chunk subtract,
//    8 FMA per 16B of W, same as before.
//  - No barrier, no LDS: 256-thread blocks, __launch_bounds__(256,8) ->
//    VGPR<=64, 8 blocks/CU = 32 waves/CU, W streams from cycle 0.

constexpr int D_DIM = 8192;
constexpr int BLOCK = 256;            // 4 waves
constexpr int ROWS_PER_BLOCK = 4;     // one row per wave
constexpr int NCHUNK = D_DIM / 4;     // 2048 float4 per row
constexpr int KPW = NCHUNK / 64;      // 32 chunks per lane per row

__global__ __launch_bounds__(BLOCK, 8)
void dyn_fused_kernel(const float* __restrict__ x_i,
                      const float* __restrict__ x_f,
                      const float* __restrict__ W,
                      const float* __restrict__ b,
                      float* __restrict__ out,
                      int M)
{
    const int tid  = threadIdx.x;
    const int wave = tid >> 6;
    const int lane = tid & 63;
    const int row  = blockIdx.x * ROWS_PER_BLOCK + wave;
    if (row >= M) return;

    const float4* Wr  = reinterpret_cast<const float4*>(W + (size_t)row * D_DIM);
    const float4* xi4 = reinterpret_cast<const float4*>(x_i);
    const float4* xf4 = reinterpret_cast<const float4*>(x_f);

    float acc_i = 0.0f;   // W[m]·x_i
    float acc_f = 0.0f;   // W[m]·x_f
    #pragma unroll 4
    for (int k = 0; k < KPW; ++k) {
        const int c = lane + k * 64;
        float4 w  = Wr[c];     // HBM stream, coalesced 1 KiB / wave instr
        float4 xi = xi4[c];    // L1/L2 hit (64 KB shared working set)
        float4 xf = xf4[c];
        acc_i = fmaf(w.x, xi.x, acc_i);
        acc_i = fmaf(w.y, xi.y, acc_i);
        acc_i = fmaf(w.z, xi.z, acc_i);
        acc_i = fmaf(w.w, xi.w, acc_i);
        acc_f = fmaf(w.x, xf.x, acc_f);
        acc_f = fmaf(w.y, xf.y, acc_f);
        acc_f = fmaf(w.z, xf.z, acc_f);
        acc_f = fmaf(w.w, xf.w, acc_f);
    }

    // 64-lane butterfly reduction of both accumulators.
    #pragma unroll
    for (int off = 32; off > 0; off >>= 1) {
        acc_i += __shfl_down(acc_i, off, 64);
        acc_f += __shfl_down(acc_f, off, 64);
    }

    if (lane == 0) {
        float z = acc_i + b[row];
        float s = 1.0f / (1.0f + expf(-z));
        out[row] = s * (1.0f - s) * (acc_f - acc_i);   // W·v = W·x_f - W·x_i
    }
}

extern "C" void kernel_launch(void* const* d_in, const int* in_sizes, int n_in,
                              void* d_out, int out_size, void* d_ws, size_t ws_size,
                              hipStream_t stream) {
    // setup_inputs order: t(1), y(M), x_i(D), x_f(D), W(M*D), b(M)
    const float* x_i = (const float*)d_in[2];
    const float* x_f = (const float*)d_in[3];
    const float* W   = (const float*)d_in[4];
    const float* b   = (const float*)d_in[5];
    float* out = (float*)d_out;
    const int M = out_size;   // 8192

    const int grid = (M + ROWS_PER_BLOCK - 1) / ROWS_PER_BLOCK;  // 2048
    dyn_fused_kernel<<<grid, BLOCK, 0, stream>>>(x_i, x_f, W, b, out, M);
}